// Round 12
// baseline (496.708 us; speedup 1.0000x reference)
//
#include <hip/hip_runtime.h>

// Problem constants
#define NB    32
#define CDIM  256
#define HWSZ  4096                 // 64*64
#define NPOS  131072
#define KCODES 1024
#define QELEMS ((size_t)NB*CDIM*HWSZ)   // 33554432
#define IDX_OFF QELEMS
#define DIFF_OFF (QELEMS + NPOS)
// B-image: 2 groups x [2 regions x 16 kc x 2 kh x 512 codes x 16B] = 1 MB
#define EBYTES 1048576
#define E2F_OFF (EBYTES/4)          // float offset 262144, e2 table (4 KB)
#define TAB_BYTE (EBYTES + 4096)    // u64 argmin table, 131072 x 8B = 1 MB

// LDS map (stage1): A 128 KB + scratch = 138.5 KB -> 1 block/CU
#define X2P   131072                // x2 partials [4][128] f32 = 2 KB
#define X2T   133120                // x2 totals  [128] f32
#define MVOFF 133632                // merge vals [8][128] f32 = 4 KB
#define MIOFF 137728                // merge idx  [8][128] i32 = 4 KB
#define LDSSZ 141824

typedef _Float16       f16x8  __attribute__((ext_vector_type(8)));
typedef float          f32x16 __attribute__((ext_vector_type(16)));
typedef unsigned short u16x8  __attribute__((ext_vector_type(8)));

static __device__ inline unsigned short f2h(float f) {
    _Float16 h = (_Float16)f;
    return __builtin_bit_cast(unsigned short, h);
}

// ---------------------------------------------------------------------------
// prep_embed: 2-region B-image (eh | el*64), grouped 2 x 512 codes, laid out
// exactly as stage1 reads it. Also e2[k], argmin-table init, diff zero.
// Region layout: byte = g2*524288 + r*262144 + kc*16384 + kh*8192 + ck*16 + sub*2
// ---------------------------------------------------------------------------
__global__ __launch_bounds__(64) void vq_prep_embed(const float* __restrict__ embed,
                                                    float* __restrict__ out) {
    const int k = blockIdx.x;
    const int lane = threadIdx.x;
    const float4 v = *reinterpret_cast<const float4*>(embed + (size_t)k * CDIM + lane * 4);

    unsigned char* __restrict__ ebuf = (unsigned char*)out;

    _Float16 h0 = (_Float16)v.x, h1 = (_Float16)v.y, h2 = (_Float16)v.z, h3 = (_Float16)v.w;
    ushort4 hv = { __builtin_bit_cast(unsigned short, h0), __builtin_bit_cast(unsigned short, h1),
                   __builtin_bit_cast(unsigned short, h2), __builtin_bit_cast(unsigned short, h3) };
    ushort4 lv = { f2h((v.x - (float)h0) * 64.0f), f2h((v.y - (float)h1) * 64.0f),
                   f2h((v.z - (float)h2) * 64.0f), f2h((v.w - (float)h3) * 64.0f) };

    const int g2 = k >> 9;
    const int ck = k & 511;
    const int c0  = lane * 4;
    const int kc  = c0 >> 4;
    const int kh  = (c0 >> 3) & 1;
    const int sub = c0 & 7;
    const size_t base = (size_t)g2 * 524288 + (size_t)kc * 16384 + kh * 8192
                      + (size_t)ck * 16 + sub * 2;
    *reinterpret_cast<ushort4*>(ebuf + base)          = hv;   // eh
    *reinterpret_cast<ushort4*>(ebuf + base + 262144) = lv;   // el*64

    float s = v.x * v.x + v.y * v.y + v.z * v.z + v.w * v.w;
    #pragma unroll
    for (int m = 1; m < 64; m <<= 1) s += __shfl_xor(s, m, 64);
    if (lane == 0) out[E2F_OFF + k] = s;

    // argmin table init (1024 blocks x 64 lanes x 2 = 131072 entries)
    unsigned long long* tab = (unsigned long long*)((unsigned char*)out + TAB_BYTE);
    const int i0 = (k * 64 + lane) * 2;
    tab[i0]     = ~0ULL;
    tab[i0 + 1] = ~0ULL;
    if (k == 0 && lane == 0) out[DIFF_OFF] = 0.0f;
}

// ---------------------------------------------------------------------------
// stage1: fused fp16-split 32x32x16 MFMA distance + argmin.
// Grid 2048 = 2 code-groups x 1024 position-partitions. Block: 512 thr =
// 8 waves, 128 positions x 512 codes; wave w = 128 pos x codes [w*64,w*64+64).
// acc[4][2] = 128 AGPR (2 waves/SIMD, no launch-bounds cap -> no spill).
// A (x, fp16 limbs xh | xl*64) in LDS, read-only after prologue.
// B from global(L2) to regs, 2-deep prefetch; eh chunk reused for seg0 AND
// seg2 (in-reg *1/64) -> B-stream 512 KB/block; x 128 KB. NO loop barriers.
// Cross-group merge via packed-u64 atomicMin table (r8-proven).
// ---------------------------------------------------------------------------
__global__ __launch_bounds__(512) void vq_stage1(const float* __restrict__ x,
                                                 float* __restrict__ out) {
    __shared__ __align__(16) unsigned char lds[LDSSZ];

    const unsigned char* __restrict__ ebuf = (const unsigned char*)out;
    const float* __restrict__ e2buf = out + E2F_OFF;
    unsigned long long* __restrict__ tab =
        (unsigned long long*)((unsigned char*)out + TAB_BYTE);

    const int t     = threadIdx.x;
    const int lane  = t & 63;
    const int col32 = lane & 31;
    const int hi    = lane >> 5;
    const int widx  = t >> 6;              // wave 0..7 : 64-code slice

    const int g2   = blockIdx.x & 1;       // code group (512 codes)
    const int p    = blockIdx.x >> 1;      // position partition
    const int pos0 = p * 128;
    const int n    = pos0 >> 12;
    const int hw0  = pos0 & 4095;
    const float* __restrict__ xbase = x + (size_t)n * (CDIM * HWSZ) + hw0;

    // ---- A staging: x fp32 -> fp16 (xh | xl*64), [2 limb][16 kc][2 kh][128 pos][16B]
    {
        const int i = t & 127;             // position (coalesced)
        const int g = t >> 7;              // channel group 0..3 (64 ch each)
        float x2p = 0.f;
        #pragma unroll
        for (int j = 0; j < 8; ++j) {
            const int c0 = g * 64 + j * 8;
            u16x8 hv, lv;
            #pragma unroll
            for (int q = 0; q < 8; ++q) {
                float vv = xbase[(size_t)(c0 + q) * HWSZ + i];
                x2p = fmaf(vv, vv, x2p);
                _Float16 hh = (_Float16)vv;
                hv[q] = __builtin_bit_cast(unsigned short, hh);
                lv[q] = f2h((vv - (float)hh) * 64.0f);
            }
            const int byte = (c0 >> 4) * 4096 + ((c0 >> 3) & 1) * 2048 + i * 16;
            *reinterpret_cast<u16x8*>(lds + byte)         = hv;   // xh
            *reinterpret_cast<u16x8*>(lds + byte + 65536) = lv;   // xl*64
        }
        ((float*)(lds + X2P))[g * 128 + i] = x2p;
    }
    __syncthreads();

    if (t < 128) {
        const float* pp = (const float*)(lds + X2P);
        ((float*)(lds + X2T))[t] = pp[t] + pp[128 + t] + pp[256 + t] + pp[384 + t];
    }
    __syncthreads();

    f32x16 acc[4][2];
    #pragma unroll
    for (int ra = 0; ra < 4; ++ra)
        #pragma unroll
        for (int cb = 0; cb < 2; ++cb)
            #pragma unroll
            for (int r = 0; r < 16; ++r) acc[ra][cb][r] = 0.f;

    // B frag: bl + r*262144 + kc*16384 + cb*512  (code = widx*64 + cb*32 + col32)
    const unsigned char* __restrict__ bl =
        ebuf + (size_t)g2 * 524288 + (size_t)(widx * 64 + col32) * 16 + hi * 8192;
    auto B = [&](int r, int kc, int cb) {
        return *reinterpret_cast<const f16x8*>(bl + r * 262144 + kc * 16384 + cb * 512);
    };
    // A frag: row = ra*32+col32, channel = kc*16 + hi*8 + j
    const int abase = hi * 2048 + col32 * 16;
    auto A = [&](int limb, int kc, int ra) {
        return *reinterpret_cast<const f16x8*>(lds + limb * 65536 + kc * 4096 + abase + ra * 512);
    };

#define MFMA8(A0,A1,A2,A3,B0,B1)                                                    \
    __builtin_amdgcn_s_setprio(1);                                                  \
    acc[0][0] = __builtin_amdgcn_mfma_f32_32x32x16_f16(A0, B0, acc[0][0], 0, 0, 0); \
    acc[0][1] = __builtin_amdgcn_mfma_f32_32x32x16_f16(A0, B1, acc[0][1], 0, 0, 0); \
    acc[1][0] = __builtin_amdgcn_mfma_f32_32x32x16_f16(A1, B0, acc[1][0], 0, 0, 0); \
    acc[1][1] = __builtin_amdgcn_mfma_f32_32x32x16_f16(A1, B1, acc[1][1], 0, 0, 0); \
    acc[2][0] = __builtin_amdgcn_mfma_f32_32x32x16_f16(A2, B0, acc[2][0], 0, 0, 0); \
    acc[2][1] = __builtin_amdgcn_mfma_f32_32x32x16_f16(A2, B1, acc[2][1], 0, 0, 0); \
    acc[3][0] = __builtin_amdgcn_mfma_f32_32x32x16_f16(A3, B0, acc[3][0], 0, 0, 0); \
    acc[3][1] = __builtin_amdgcn_mfma_f32_32x32x16_f16(A3, B1, acc[3][1], 0, 0, 0); \
    __builtin_amdgcn_s_setprio(0);

    f16x8 nb0 = B(0, 0, 0), nb1 = B(0, 0, 1);

    // ---- phase 1: eh chunks, each used twice: xh*eh, then (xl*64)*(eh/64)
    #pragma unroll 4
    for (int kc = 0; kc < 16; ++kc) {
        f16x8 b0 = nb0, b1 = nb1;
        const int kn = (kc + 1) & 15;
        const int rn = (kc == 15) ? 1 : 0;
        nb0 = B(rn, kn, 0); nb1 = B(rn, kn, 1);

        f16x8 a0 = A(0, kc, 0), a1 = A(0, kc, 1), a2 = A(0, kc, 2), a3 = A(0, kc, 3);
        MFMA8(a0, a1, a2, a3, b0, b1)

        b0 *= (_Float16)0.015625f;
        b1 *= (_Float16)0.015625f;
        a0 = A(1, kc, 0); a1 = A(1, kc, 1); a2 = A(1, kc, 2); a3 = A(1, kc, 3);
        MFMA8(a0, a1, a2, a3, b0, b1)
    }

    // ---- phase 2: el*64 chunks: xh * (el*64) / 64
    #pragma unroll 4
    for (int kc = 0; kc < 16; ++kc) {
        f16x8 b0 = nb0 * (_Float16)0.015625f;
        f16x8 b1 = nb1 * (_Float16)0.015625f;
        const int kn = (kc + 1) & 15;
        nb0 = B(1, kn, 0); nb1 = B(1, kn, 1);

        f16x8 a0 = A(0, kc, 0), a1 = A(0, kc, 1), a2 = A(0, kc, 2), a3 = A(0, kc, 3);
        MFMA8(a0, a1, a2, a3, b0, b1)
    }
#undef MFMA8

    // ---- epilogue: scores, in-wave argmin, cross-wave merge, atomicMin
    const float* x2t = (const float*)(lds + X2T);
    const float e2v0 = e2buf[g2 * 512 + widx * 64 + col32];
    const float e2v1 = e2buf[g2 * 512 + widx * 64 + 32 + col32];
    const int code0 = g2 * 512 + widx * 64 + col32;

    float* mv = (float*)(lds + MVOFF);
    int*   mi = (int*)(lds + MIOFF);

    #pragma unroll
    for (int ra = 0; ra < 4; ++ra) {
        #pragma unroll
        for (int reg = 0; reg < 16; ++reg) {
            const int row = ra * 32 + (reg & 3) + 8 * (reg >> 2) + 4 * hi;
            const float x2 = x2t[row];
            float bv_ = fmaxf((x2 - 2.0f * acc[ra][0][reg]) + e2v0, 0.0f);
            int   bi_ = code0;
            const float s1 = fmaxf((x2 - 2.0f * acc[ra][1][reg]) + e2v1, 0.0f);
            if (s1 < bv_) { bv_ = s1; bi_ = code0 + 32; }
            #pragma unroll
            for (int m = 1; m < 32; m <<= 1) {
                float ov = __shfl_xor(bv_, m, 64);
                int   oi = __shfl_xor(bi_, m, 64);
                if (ov < bv_ || (ov == bv_ && oi < bi_)) { bv_ = ov; bi_ = oi; }
            }
            if (col32 == 0) {
                mv[widx * 128 + row] = bv_;
                mi[widx * 128 + row] = bi_;
            }
        }
    }

    __syncthreads();
    if (t < 128) {
        float bv_ = mv[t];
        int   bi_ = mi[t];
        #pragma unroll
        for (int w = 1; w < 8; ++w) {
            const float ov = mv[w * 128 + t];
            const int   oi = mi[w * 128 + t];
            if (ov < bv_ || (ov == bv_ && oi < bi_)) { bv_ = ov; bi_ = oi; }
        }
        const unsigned long long pack =
            ((unsigned long long)__float_as_uint(bv_) << 32) | (unsigned)bi_;
        atomicMin(&tab[pos0 + t], pack);
    }
}

// ---------------------------------------------------------------------------
// extract: unpack argmin table -> idx floats; reduce diff = sum(min dist)/N.
// ---------------------------------------------------------------------------
__global__ __launch_bounds__(256) void vq_extract(float* __restrict__ out) {
    const unsigned long long* __restrict__ tab =
        (const unsigned long long*)((unsigned char*)out + TAB_BYTE);
    const int p = blockIdx.x * 256 + threadIdx.x;
    const unsigned long long v = tab[p];
    out[IDX_OFF + p] = (float)(unsigned)(v & 0xFFFFFFFFu);
    float d = __uint_as_float((unsigned)(v >> 32));

    #pragma unroll
    for (int m = 1; m < 64; m <<= 1) d += __shfl_xor(d, m, 64);
    __shared__ float red[4];
    const int lane = threadIdx.x & 63;
    const int w = threadIdx.x >> 6;
    if (lane == 0) red[w] = d;
    __syncthreads();
    if (threadIdx.x == 0) {
        float s = red[0] + red[1] + red[2] + red[3];
        atomicAdd(out + DIFF_OFF, s * (1.0f / 33554432.0f));
    }
}

// ---------------------------------------------------------------------------
// gather: quantize = embed[idx] (NCHW).
// ---------------------------------------------------------------------------
__global__ __launch_bounds__(256) void vq_gather_kernel(const float* __restrict__ embed,
                                                        float* __restrict__ out) {
    const int tid = threadIdx.x;
    const int p = blockIdx.x * 256 + tid;
    const int n = p >> 12;
    const int hw = p & 4095;
    const int idx = (int)out[IDX_OFF + p];
    const float4* __restrict__ erow4 = reinterpret_cast<const float4*>(embed + (size_t)idx * CDIM);
    float* __restrict__ op = out + (size_t)n * (CDIM * HWSZ) + hw;

    #pragma unroll 8
    for (int c4 = 0; c4 < 64; ++c4) {
        const float4 e = erow4[c4];
        op[(size_t)(c4 * 4 + 0) * HWSZ] = e.x;
        op[(size_t)(c4 * 4 + 1) * HWSZ] = e.y;
        op[(size_t)(c4 * 4 + 2) * HWSZ] = e.z;
        op[(size_t)(c4 * 4 + 3) * HWSZ] = e.w;
    }
}

extern "C" void kernel_launch(void* const* d_in, const int* in_sizes, int n_in,
                              void* d_out, int out_size, void* d_ws, size_t ws_size,
                              hipStream_t stream) {
    const float* x = (const float*)d_in[0];
    const float* embed = (const float*)d_in[1];
    float* out = (float*)d_out;

    vq_prep_embed<<<KCODES, 64, 0, stream>>>(embed, out);
    vq_stage1<<<(NPOS / 128) * 2, 512, 0, stream>>>(x, out);
    vq_extract<<<NPOS / 256, 256, 0, stream>>>(out);
    vq_gather_kernel<<<NPOS / 256, 256, 0, stream>>>(embed, out);
}